// Round 1
// baseline (533.729 us; speedup 1.0000x reference)
//
#include <hip/hip_runtime.h>
#include <hip/hip_bf16.h>
#include <math.h>

#define V_SZ 32000
#define E_SZ 512
#define H_SZ 512
#define T_SZ 64
#define B_SZ 16
#define VT_SZ (V_SZ + T_SZ)       // 32064
#define TOT_SM (V_SZ + VT_SZ)     // 64064

// ws offsets (in floats)
#define WS_H0ATT 0u               // [16][512]
#define WS_GH    8192u            // [16][1536]
#define WS_E1    32768u           // [1024][512]  (b*64+t rows)
#define WS_TANHC 557056u          // [1024][512]
#define WS_EATTN 1081344u         // [16][64]
#define WS_X     1082368u         // [16][1024]  (emb | context)
#define WS_GX    1098752u         // [16][1536]
#define WS_Y     1123328u         // [16][1024]  (h1 | context)
#define WS_WT    1139712u         // [16][64]
#define WS_MB    1140736u         // [16]
#define WS_PART  1140752u         // [4][16][32000]
#define WS_GL    3188752u         // [16][32000]
#define WS_UCSV  3700752u         // [16][32064]

__device__ __forceinline__ float dot4(float4 a, float4 b) {
    return fmaf(a.x, b.x, fmaf(a.y, b.y, fmaf(a.z, b.z, a.w * b.w)));
}

// K1: h0att[b][h] = attn_b[h] + h0 . attn_W[h][:512] ; gh[b][j] = b_hh[j] + h0 . W_hh[j]
__global__ __launch_bounds__(256) void k_prep(const float* __restrict__ last_hidden,
        const float* __restrict__ attn_W, const float* __restrict__ attn_b,
        const float* __restrict__ W_hh, const float* __restrict__ b_hh,
        float* __restrict__ ws) {
    int i = blockIdx.x * 256 + threadIdx.x;      // 16*2048
    int b = i >> 11, j = i & 2047;
    const float* h0 = last_hidden + b * H_SZ;
    if (j < 512) {
        const float* wr = attn_W + j * 1024;
        float acc = attn_b[j];
        for (int k = 0; k < 512; k += 4)
            acc += dot4(*(const float4*)(h0 + k), *(const float4*)(wr + k));
        ws[WS_H0ATT + b * 512 + j] = acc;
    } else {
        int jj = j - 512;  // 0..1535
        const float* wr = W_hh + jj * 512;
        float acc = b_hh[jj];
        for (int k = 0; k < 512; k += 4)
            acc += dot4(*(const float4*)(h0 + k), *(const float4*)(wr + k));
        ws[WS_GH + b * 1536 + jj] = acc;
    }
}

// K2: enc GEMM. by = batch b (rows t=0..63), bx<8: E1 cols, bx>=8: tanh copy cols.
__global__ __launch_bounds__(256) void k_encgemm(const float* __restrict__ u,
        const float* __restrict__ attn_W, const float* __restrict__ copy_W,
        const float* __restrict__ copy_b, float* __restrict__ ws) {
    __shared__ float As[64][33];
    __shared__ float Bs[64][33];
    float* E1 = ws + WS_E1;
    float* tanhC = ws + WS_TANHC;
    int bx = blockIdx.x, by = blockIdx.y;
    int tid = threadIdx.x;
    int tm = tid & 15, tn = tid >> 4;
    float acc[4][4] = {};
    int r = tid >> 3;            // 0..31
    int c4 = (tid & 7) * 4;      // 0..28
    for (int k0 = 0; k0 < 512; k0 += 32) {
        #pragma unroll
        for (int rep = 0; rep < 2; ++rep) {
            int rr = r + rep * 32;
            float4 av = *(const float4*)(u + (rr * 16 + by) * 512 + k0 + c4);
            As[rr][c4 + 0] = av.x; As[rr][c4 + 1] = av.y;
            As[rr][c4 + 2] = av.z; As[rr][c4 + 3] = av.w;
            const float* brow = (bx < 8) ? (attn_W + (bx * 64 + rr) * 1024 + 512)
                                         : (copy_W + ((bx - 8) * 64 + rr) * 512);
            float4 bv = *(const float4*)(brow + k0 + c4);
            Bs[rr][c4 + 0] = bv.x; Bs[rr][c4 + 1] = bv.y;
            Bs[rr][c4 + 2] = bv.z; Bs[rr][c4 + 3] = bv.w;
        }
        __syncthreads();
        #pragma unroll 8
        for (int kk = 0; kk < 32; ++kk) {
            float a0 = As[tm * 4 + 0][kk], a1 = As[tm * 4 + 1][kk];
            float a2 = As[tm * 4 + 2][kk], a3 = As[tm * 4 + 3][kk];
            float b0 = Bs[tn * 4 + 0][kk], b1 = Bs[tn * 4 + 1][kk];
            float b2 = Bs[tn * 4 + 2][kk], b3 = Bs[tn * 4 + 3][kk];
            acc[0][0] = fmaf(a0, b0, acc[0][0]); acc[0][1] = fmaf(a0, b1, acc[0][1]);
            acc[0][2] = fmaf(a0, b2, acc[0][2]); acc[0][3] = fmaf(a0, b3, acc[0][3]);
            acc[1][0] = fmaf(a1, b0, acc[1][0]); acc[1][1] = fmaf(a1, b1, acc[1][1]);
            acc[1][2] = fmaf(a1, b2, acc[1][2]); acc[1][3] = fmaf(a1, b3, acc[1][3]);
            acc[2][0] = fmaf(a2, b0, acc[2][0]); acc[2][1] = fmaf(a2, b1, acc[2][1]);
            acc[2][2] = fmaf(a2, b2, acc[2][2]); acc[2][3] = fmaf(a2, b3, acc[2][3]);
            acc[3][0] = fmaf(a3, b0, acc[3][0]); acc[3][1] = fmaf(a3, b1, acc[3][1]);
            acc[3][2] = fmaf(a3, b2, acc[3][2]); acc[3][3] = fmaf(a3, b3, acc[3][3]);
        }
        __syncthreads();
    }
    #pragma unroll
    for (int i = 0; i < 4; ++i) {
        int t = tm * 4 + i;
        #pragma unroll
        for (int j = 0; j < 4; ++j) {
            int c = tn * 4 + j;
            if (bx < 8) {
                E1[(by * 64 + t) * 512 + bx * 64 + c] = acc[i][j];
            } else {
                int n2 = (bx - 8) * 64 + c;
                tanhC[(by * 64 + t) * 512 + n2] = tanhf(acc[i][j] + copy_b[n2]);
            }
        }
    }
}

// K3: attention energies e[b][t]
__global__ __launch_bounds__(256) void k_attn_e(const float* __restrict__ attn_v,
        float* __restrict__ ws) {
    int b = blockIdx.x, tchunk = blockIdx.y;
    int t = tchunk * 8 + (threadIdx.x >> 5);
    int lane = threadIdx.x & 31;
    const float* h0att = ws + WS_H0ATT + b * 512;
    const float* e1 = ws + WS_E1 + (b * 64 + t) * 512;
    float s = 0.f;
    #pragma unroll
    for (int i = 0; i < 16; ++i) {
        int h = lane + 32 * i;
        s += tanhf(h0att[h] + e1[h]) * attn_v[h];
    }
    #pragma unroll
    for (int m = 16; m >= 1; m >>= 1) s += __shfl_xor(s, m);
    if (lane == 0) ws[WS_EATTN + b * 64 + t] = s;
}

// K4: softmax over t, context, x = [emb_row | context]
__global__ __launch_bounds__(256) void k_attn_ctx(const float* __restrict__ u,
        const int* __restrict__ a_tm1, const float* __restrict__ emb,
        float* __restrict__ ws) {
    int b = blockIdx.x, tid = threadIdx.x;
    __shared__ float alpha[64];
    if (tid < 64) {
        float v = ws[WS_EATTN + b * 64 + tid];
        float m = v;
        #pragma unroll
        for (int k = 32; k >= 1; k >>= 1) m = fmaxf(m, __shfl_xor(m, k));
        float ex = expf(v - m);
        float s = ex;
        #pragma unroll
        for (int k = 32; k >= 1; k >>= 1) s += __shfl_xor(s, k);
        alpha[tid] = ex / s;
    }
    __syncthreads();
    int a = a_tm1[b];
    float* x = ws + WS_X + b * 1024;
    for (int h = tid; h < 512; h += 256) {
        float ctx = 0.f;
        #pragma unroll 8
        for (int t = 0; t < 64; ++t) ctx += alpha[t] * u[(t * 16 + b) * 512 + h];
        x[512 + h] = ctx;
        x[h] = emb[a * 512 + h];
    }
}

// K5: gx[b][j] = b_ih[j] + x[b] . W_ih[j]
__global__ __launch_bounds__(256) void k_gx(const float* __restrict__ W_ih,
        const float* __restrict__ b_ih, float* __restrict__ ws) {
    int j = blockIdx.x * 16 + (threadIdx.x >> 4);
    int b = threadIdx.x & 15;
    const float* xr = ws + WS_X + b * 1024;
    const float* wr = W_ih + j * 1024;
    float acc = b_ih[j];
    for (int k = 0; k < 1024; k += 4)
        acc += dot4(*(const float4*)(xr + k), *(const float4*)(wr + k));
    ws[WS_GX + b * 1536 + j] = acc;
}

// K6: GRU combine -> h1, write outputs + y = [h1 | context]
__global__ __launch_bounds__(256) void k_h1(const float* __restrict__ last_hidden,
        float* __restrict__ ws, float* __restrict__ out) {
    int i = blockIdx.x * 256 + threadIdx.x;   // < 8192
    int b = i >> 9, h = i & 511;
    const float* gx = ws + WS_GX + b * 1536;
    const float* gh = ws + WS_GH + b * 1536;
    float r = 1.f / (1.f + expf(-(gx[h] + gh[h])));
    float z = 1.f / (1.f + expf(-(gx[512 + h] + gh[512 + h])));
    float n = tanhf(gx[1024 + h] + r * gh[1024 + h]);
    float h0v = last_hidden[b * 512 + h];
    float h1 = (1.f - z) * n + z * h0v;
    out[i] = h1;
    out[8192 + i] = h1;
    ws[WS_Y + b * 1024 + h] = h1;
    ws[WS_Y + b * 1024 + 512 + h] = ws[WS_X + b * 1024 + 512 + h];
}

// K7: gen score partials, split-K (4 quarters of 256)
__global__ __launch_bounds__(256) void k_gen(const float* __restrict__ proj_W,
        float* __restrict__ ws) {
    __shared__ float ys[16][256];
    int kq = blockIdx.y, tid = threadIdx.x;
    for (int i = tid; i < 4096; i += 256) {
        int b = i >> 8, c = i & 255;
        ys[b][c] = ws[WS_Y + b * 1024 + kq * 256 + c];
    }
    __syncthreads();
    int v0 = blockIdx.x * 512 + tid;
    int v1 = v0 + 256;
    bool g1 = v1 < V_SZ;
    float acc0[16] = {}, acc1[16] = {};
    const float* w0p = proj_W + (size_t)v0 * 1024 + kq * 256;
    const float* w1p = proj_W + (size_t)v1 * 1024 + kq * 256;
    for (int c = 0; c < 256; c += 4) {
        float4 w0 = *(const float4*)(w0p + c);
        float4 w1 = g1 ? *(const float4*)(w1p + c) : make_float4(0.f, 0.f, 0.f, 0.f);
        #pragma unroll
        for (int b = 0; b < 16; ++b) {
            float4 yv = *(const float4*)(&ys[b][c]);
            acc0[b] = fmaf(w0.x, yv.x, fmaf(w0.y, yv.y, fmaf(w0.z, yv.z, fmaf(w0.w, yv.w, acc0[b]))));
            acc1[b] = fmaf(w1.x, yv.x, fmaf(w1.y, yv.y, fmaf(w1.z, yv.z, fmaf(w1.w, yv.w, acc1[b]))));
        }
    }
    float* part = ws + WS_PART;
    #pragma unroll
    for (int b = 0; b < 16; ++b) {
        part[(size_t)(kq * 16 + b) * V_SZ + v0] = acc0[b];
        if (g1) part[(size_t)(kq * 16 + b) * V_SZ + v1] = acc1[b];
    }
}

// K8: reduce partials + bias -> gen_logit
__global__ __launch_bounds__(256) void k_genred(const float* __restrict__ proj_b,
        float* __restrict__ ws) {
    int idx = blockIdx.x * 256 + threadIdx.x;   // < 512000
    int b = idx / V_SZ, v = idx - b * V_SZ;
    const float* part = ws + WS_PART;
    float g = proj_b[v];
    #pragma unroll
    for (int kq = 0; kq < 4; ++kq) g += part[(size_t)(kq * 16 + b) * V_SZ + v];
    ws[WS_GL + (size_t)b * V_SZ + v] = g;
}

// K9: copy scores -> exp weights w_t, m_b
__global__ __launch_bounds__(256) void k_copyscore(float* __restrict__ ws) {
    int b = blockIdx.x, tid = threadIdx.x;
    int t = tid >> 2, q = tid & 3;
    const float* tc = ws + WS_TANHC + (b * 64 + t) * 512;
    const float* h1 = ws + WS_Y + b * 1024;
    float s = 0.f;
    for (int i = 0; i < 128; i += 4) {
        int h = q * 128 + i;
        s += dot4(*(const float4*)(tc + h), *(const float4*)(h1 + h));
    }
    s += __shfl_xor(s, 1);
    s += __shfl_xor(s, 2);
    __shared__ float uc[64];
    if (q == 0) uc[t] = s;
    __syncthreads();
    if (tid < 64) {
        float v = uc[tid];
        float m = v;
        #pragma unroll
        for (int k = 32; k >= 1; k >>= 1) m = fmaxf(m, __shfl_xor(m, k));
        ws[WS_WT + b * 64 + tid] = expf(v - m);
        if (tid == 0) ws[WS_MB + b] = m;
    }
}

// K10: ucs_v[b][v] = log(sum_t w[t]*sparse[b][t][v]) + m_b
__global__ __launch_bounds__(256) void k_ucsv(const float* __restrict__ sparse,
        float* __restrict__ ws) {
    int b = blockIdx.y;
    int v = blockIdx.x * 256 + threadIdx.x;
    __shared__ float wsm[64];
    if (threadIdx.x < 64) wsm[threadIdx.x] = ws[WS_WT + b * 64 + threadIdx.x];
    __syncthreads();
    if (v >= VT_SZ) return;
    const float* sp = sparse + (size_t)b * 64 * VT_SZ + v;
    float acc = 0.f;
    #pragma unroll 8
    for (int t = 0; t < 64; ++t) acc = fmaf(wsm[t], sp[(size_t)t * VT_SZ], acc);
    ws[WS_UCSV + (size_t)b * VT_SZ + v] = logf(acc) + ws[WS_MB + b];
}

// K11: joint softmax over [gen_logit | ucs_v], merge to proba
__global__ __launch_bounds__(1024) void k_final(float* __restrict__ ws, float* __restrict__ out) {
    int b = blockIdx.x, tid = threadIdx.x;
    const float* gl = ws + WS_GL + (size_t)b * V_SZ;
    const float* uv = ws + WS_UCSV + (size_t)b * VT_SZ;
    __shared__ float red[16];
    float m = -3.0e38f;
    for (int i = tid; i < TOT_SM; i += 1024) {
        float v = (i < V_SZ) ? gl[i] : uv[i - V_SZ];
        m = fmaxf(m, v);
    }
    #pragma unroll
    for (int k = 32; k >= 1; k >>= 1) m = fmaxf(m, __shfl_xor(m, k));
    if ((tid & 63) == 0) red[tid >> 6] = m;
    __syncthreads();
    float M = red[0];
    #pragma unroll
    for (int i = 1; i < 16; ++i) M = fmaxf(M, red[i]);
    __syncthreads();
    float s = 0.f;
    for (int i = tid; i < TOT_SM; i += 1024) {
        float v = (i < V_SZ) ? gl[i] : uv[i - V_SZ];
        s += expf(v - M);
    }
    #pragma unroll
    for (int k = 32; k >= 1; k >>= 1) s += __shfl_xor(s, k);
    if ((tid & 63) == 0) red[tid >> 6] = s;
    __syncthreads();
    float S = 0.f;
    #pragma unroll
    for (int i = 0; i < 16; ++i) S += red[i];
    float invS = 1.f / S;
    float* ob = out + 16384 + (size_t)b * VT_SZ;
    for (int i = tid; i < VT_SZ; i += 1024) {
        float cp = expf(uv[i] - M) * invS;
        float p = (i < V_SZ) ? fmaf(expf(gl[i] - M), invS, cp) : cp;
        ob[i] = p;
    }
}

extern "C" void kernel_launch(void* const* d_in, const int* in_sizes, int n_in,
                              void* d_out, int out_size, void* d_ws, size_t ws_size,
                              hipStream_t stream) {
    (void)in_sizes; (void)n_in; (void)out_size; (void)ws_size;
    const float* u_enc   = (const float*)d_in[0];
    const int*   a_tm1   = (const int*)d_in[1];
    const float* last_h  = (const float*)d_in[2];
    // d_in[3] u_input_np unused
    const float* sparse  = (const float*)d_in[4];
    const float* emb     = (const float*)d_in[5];
    const float* W_ih    = (const float*)d_in[6];
    const float* b_ih    = (const float*)d_in[7];
    const float* W_hh    = (const float*)d_in[8];
    const float* b_hh    = (const float*)d_in[9];
    const float* proj_W  = (const float*)d_in[10];
    const float* proj_b  = (const float*)d_in[11];
    const float* attn_W  = (const float*)d_in[12];
    const float* attn_b  = (const float*)d_in[13];
    const float* attn_v  = (const float*)d_in[14];
    const float* copy_W  = (const float*)d_in[15];
    const float* copy_b  = (const float*)d_in[16];
    float* ws  = (float*)d_ws;
    float* out = (float*)d_out;

    hipLaunchKernelGGL(k_prep, dim3(128), dim3(256), 0, stream,
                       last_h, attn_W, attn_b, W_hh, b_hh, ws);
    hipLaunchKernelGGL(k_encgemm, dim3(16, 16), dim3(256), 0, stream,
                       u_enc, attn_W, copy_W, copy_b, ws);
    hipLaunchKernelGGL(k_attn_e, dim3(16, 8), dim3(256), 0, stream, attn_v, ws);
    hipLaunchKernelGGL(k_attn_ctx, dim3(16), dim3(256), 0, stream, u_enc, a_tm1, emb, ws);
    hipLaunchKernelGGL(k_gx, dim3(96), dim3(256), 0, stream, W_ih, b_ih, ws);
    hipLaunchKernelGGL(k_h1, dim3(32), dim3(256), 0, stream, last_h, ws, out);
    hipLaunchKernelGGL(k_gen, dim3(63, 4), dim3(256), 0, stream, proj_W, ws);
    hipLaunchKernelGGL(k_genred, dim3(2000), dim3(256), 0, stream, proj_b, ws);
    hipLaunchKernelGGL(k_copyscore, dim3(16), dim3(256), 0, stream, ws);
    hipLaunchKernelGGL(k_ucsv, dim3(126, 16), dim3(256), 0, stream, sparse, ws);
    hipLaunchKernelGGL(k_final, dim3(16), dim3(1024), 0, stream, ws, out);
}

// Round 3
// 497.054 us; speedup vs baseline: 1.0738x; 1.0738x over previous
//
#include <hip/hip_runtime.h>
#include <hip/hip_bf16.h>
#include <math.h>

#define V_SZ 32000
#define E_SZ 512
#define H_SZ 512
#define T_SZ 64
#define B_SZ 16
#define VT_SZ (V_SZ + T_SZ)       // 32064
#define TOT_SM (V_SZ + VT_SZ)     // 64064

// ws offsets (in floats)
#define WS_H0ATT 0u               // [16][512]
#define WS_GH    8192u            // [16][1536]
#define WS_E1    32768u           // [1024][512]  (b*64+t rows)
#define WS_TANHC 557056u          // [1024][512]
#define WS_EATTN 1081344u         // [16][64]
#define WS_X     1082368u         // [16][1024]  (emb | context)
#define WS_GX    1098752u         // [16][1536]
#define WS_Y     1123328u         // [16][1024]  (h1 | context)
#define WS_WT    1139712u         // [16][64]
#define WS_MB    1140736u         // [16]
#define WS_FST   1140752u         // [16][8][2] softmax chunk stats
#define WS_GL    3188752u         // [16][32000]
#define WS_UCSV  3700752u         // [16][32064]

__device__ __forceinline__ float dot4(float4 a, float4 b) {
    return fmaf(a.x, b.x, fmaf(a.y, b.y, fmaf(a.z, b.z, a.w * b.w)));
}

// ---------------------------------------------------------------------------
// Wave-cooperative GEMV: one wave computes 16 rows x 16 batch.
// lane = (ks = lane&15 -> K slice, s = lane>>4 -> batch quad).
// W row reads: 16 lanes x float4 = 256B contiguous, broadcast over 4 quads.
// acc[16][4] statically indexed; 4-stage shfl_xor butterfly reduces over the
// 16 k-lanes with row-halving so lane L ends with row (L&15), b = 4*(L>>4)+n.
// ---------------------------------------------------------------------------
template<int NPASS>
__device__ __forceinline__ void wave_gemv16(
        const float* __restrict__ W,      // pre-offset to rowbase*ldw (+col off)
        int ldw,
        const float* __restrict__ y,      // [16][ldy]
        int ldy,
        const float* __restrict__ bias,   // pre-offset to rowbase
        float* __restrict__ out, int ostride, int rowglob) {
    int lane = threadIdx.x & 63;
    int ks = lane & 15, s = lane >> 4;
    float acc[16][4];
    #pragma unroll
    for (int r = 0; r < 16; ++r)
        #pragma unroll
        for (int n = 0; n < 4; ++n) acc[r][n] = 0.f;

    for (int p = 0; p < NPASS; ++p) {
        int kk = ks * 4 + p * 64;
        float4 y4[4];
        #pragma unroll
        for (int n = 0; n < 4; ++n)
            y4[n] = *(const float4*)(y + (4 * s + n) * ldy + kk);
        #pragma unroll
        for (int r = 0; r < 16; ++r) {
            float4 w4 = *(const float4*)(W + r * ldw + kk);
            #pragma unroll
            for (int n = 0; n < 4; ++n)
                acc[r][n] = fmaf(w4.x, y4[n].x, fmaf(w4.y, y4[n].y,
                            fmaf(w4.z, y4[n].z, fmaf(w4.w, y4[n].w, acc[r][n]))));
        }
    }
    // butterfly reduce across the 16 k-lanes, halving rows each stage
    float a8[8][4];
    #pragma unroll
    for (int r = 0; r < 8; ++r)
        #pragma unroll
        for (int n = 0; n < 4; ++n) {
            float keep = (lane & 8) ? acc[r + 8][n] : acc[r][n];
            float send = (lane & 8) ? acc[r][n] : acc[r + 8][n];
            a8[r][n] = keep + __shfl_xor(send, 8);
        }
    float a4_[4][4];
    #pragma unroll
    for (int r = 0; r < 4; ++r)
        #pragma unroll
        for (int n = 0; n < 4; ++n) {
            float keep = (lane & 4) ? a8[r + 4][n] : a8[r][n];
            float send = (lane & 4) ? a8[r][n] : a8[r + 4][n];
            a4_[r][n] = keep + __shfl_xor(send, 4);
        }
    float a2_[2][4];
    #pragma unroll
    for (int r = 0; r < 2; ++r)
        #pragma unroll
        for (int n = 0; n < 4; ++n) {
            float keep = (lane & 2) ? a4_[r + 2][n] : a4_[r][n];
            float send = (lane & 2) ? a4_[r][n] : a4_[r + 2][n];
            a2_[r][n] = keep + __shfl_xor(send, 2);
        }
    float a1_[4];
    #pragma unroll
    for (int n = 0; n < 4; ++n) {
        float keep = (lane & 1) ? a2_[1][n] : a2_[0][n];
        float send = (lane & 1) ? a2_[0][n] : a2_[1][n];
        a1_[n] = keep + __shfl_xor(send, 1);
    }
    int rf = lane & 15;
    float bv = bias[rf];
    #pragma unroll
    for (int n = 0; n < 4; ++n)
        out[(size_t)(4 * s + n) * ostride + rowglob + rf] = a1_[n] + bv;
}

// K1: h0att = attn_b + h0 @ attn_W[:, :512].T ; gh = b_hh + h0 @ W_hh.T
__global__ __launch_bounds__(256) void k_prep2(const float* __restrict__ last_hidden,
        const float* __restrict__ attn_W, const float* __restrict__ attn_b,
        const float* __restrict__ W_hh, const float* __restrict__ b_hh,
        float* __restrict__ ws) {
    int gw = blockIdx.x * 4 + (threadIdx.x >> 6);
    int rowbase = gw * 16;
    if (rowbase < 512) {
        wave_gemv16<8>(attn_W + (size_t)rowbase * 1024, 1024,
                       last_hidden, 512, attn_b + rowbase,
                       ws + WS_H0ATT, 512, rowbase);
    } else {
        int r2 = rowbase - 512;
        wave_gemv16<8>(W_hh + (size_t)r2 * 512, 512,
                       last_hidden, 512, b_hh + r2,
                       ws + WS_GH, 1536, r2);
    }
}

// K2: enc GEMM. by = batch b (rows t=0..63), bx<8: E1 cols, bx>=8: tanh copy cols.
__global__ __launch_bounds__(256) void k_encgemm(const float* __restrict__ u,
        const float* __restrict__ attn_W, const float* __restrict__ copy_W,
        const float* __restrict__ copy_b, float* __restrict__ ws) {
    __shared__ float As[64][33];
    __shared__ float Bs[64][33];
    float* E1 = ws + WS_E1;
    float* tanhC = ws + WS_TANHC;
    int bx = blockIdx.x, by = blockIdx.y;
    int tid = threadIdx.x;
    int tm = tid & 15, tn = tid >> 4;
    float acc[4][4] = {};
    int r = tid >> 3;            // 0..31
    int c4 = (tid & 7) * 4;      // 0..28
    for (int k0 = 0; k0 < 512; k0 += 32) {
        #pragma unroll
        for (int rep = 0; rep < 2; ++rep) {
            int rr = r + rep * 32;
            float4 av = *(const float4*)(u + (rr * 16 + by) * 512 + k0 + c4);
            As[rr][c4 + 0] = av.x; As[rr][c4 + 1] = av.y;
            As[rr][c4 + 2] = av.z; As[rr][c4 + 3] = av.w;
            const float* brow = (bx < 8) ? (attn_W + (bx * 64 + rr) * 1024 + 512)
                                         : (copy_W + ((bx - 8) * 64 + rr) * 512);
            float4 bv = *(const float4*)(brow + k0 + c4);
            Bs[rr][c4 + 0] = bv.x; Bs[rr][c4 + 1] = bv.y;
            Bs[rr][c4 + 2] = bv.z; Bs[rr][c4 + 3] = bv.w;
        }
        __syncthreads();
        #pragma unroll 8
        for (int kk = 0; kk < 32; ++kk) {
            float a0 = As[tm * 4 + 0][kk], a1 = As[tm * 4 + 1][kk];
            float a2 = As[tm * 4 + 2][kk], a3 = As[tm * 4 + 3][kk];
            float b0 = Bs[tn * 4 + 0][kk], b1 = Bs[tn * 4 + 1][kk];
            float b2 = Bs[tn * 4 + 2][kk], b3 = Bs[tn * 4 + 3][kk];
            acc[0][0] = fmaf(a0, b0, acc[0][0]); acc[0][1] = fmaf(a0, b1, acc[0][1]);
            acc[0][2] = fmaf(a0, b2, acc[0][2]); acc[0][3] = fmaf(a0, b3, acc[0][3]);
            acc[1][0] = fmaf(a1, b0, acc[1][0]); acc[1][1] = fmaf(a1, b1, acc[1][1]);
            acc[1][2] = fmaf(a1, b2, acc[1][2]); acc[1][3] = fmaf(a1, b3, acc[1][3]);
            acc[2][0] = fmaf(a2, b0, acc[2][0]); acc[2][1] = fmaf(a2, b1, acc[2][1]);
            acc[2][2] = fmaf(a2, b2, acc[2][2]); acc[2][3] = fmaf(a2, b3, acc[2][3]);
            acc[3][0] = fmaf(a3, b0, acc[3][0]); acc[3][1] = fmaf(a3, b1, acc[3][1]);
            acc[3][2] = fmaf(a3, b2, acc[3][2]); acc[3][3] = fmaf(a3, b3, acc[3][3]);
        }
        __syncthreads();
    }
    #pragma unroll
    for (int i = 0; i < 4; ++i) {
        int t = tm * 4 + i;
        #pragma unroll
        for (int j = 0; j < 4; ++j) {
            int c = tn * 4 + j;
            if (bx < 8) {
                E1[(by * 64 + t) * 512 + bx * 64 + c] = acc[i][j];
            } else {
                int n2 = (bx - 8) * 64 + c;
                tanhC[(by * 64 + t) * 512 + n2] = tanhf(acc[i][j] + copy_b[n2]);
            }
        }
    }
}

// K3: attention energies e[b][t]
__global__ __launch_bounds__(256) void k_attn_e(const float* __restrict__ attn_v,
        float* __restrict__ ws) {
    int b = blockIdx.x, tchunk = blockIdx.y;
    int t = tchunk * 8 + (threadIdx.x >> 5);
    int lane = threadIdx.x & 31;
    const float* h0att = ws + WS_H0ATT + b * 512;
    const float* e1 = ws + WS_E1 + (b * 64 + t) * 512;
    float s = 0.f;
    #pragma unroll
    for (int i = 0; i < 16; ++i) {
        int h = lane + 32 * i;
        s += tanhf(h0att[h] + e1[h]) * attn_v[h];
    }
    #pragma unroll
    for (int m = 16; m >= 1; m >>= 1) s += __shfl_xor(s, m);
    if (lane == 0) ws[WS_EATTN + b * 64 + t] = s;
}

// K4: softmax over t, context, x = [emb_row | context]
__global__ __launch_bounds__(256) void k_attn_ctx(const float* __restrict__ u,
        const int* __restrict__ a_tm1, const float* __restrict__ emb,
        float* __restrict__ ws) {
    int b = blockIdx.x, tid = threadIdx.x;
    __shared__ float alpha[64];
    if (tid < 64) {
        float v = ws[WS_EATTN + b * 64 + tid];
        float m = v;
        #pragma unroll
        for (int k = 32; k >= 1; k >>= 1) m = fmaxf(m, __shfl_xor(m, k));
        float ex = expf(v - m);
        float s = ex;
        #pragma unroll
        for (int k = 32; k >= 1; k >>= 1) s += __shfl_xor(s, k);
        alpha[tid] = ex / s;
    }
    __syncthreads();
    int a = a_tm1[b];
    float* x = ws + WS_X + b * 1024;
    for (int h = tid; h < 512; h += 256) {
        float ctx = 0.f;
        #pragma unroll 8
        for (int t = 0; t < 64; ++t) ctx += alpha[t] * u[(t * 16 + b) * 512 + h];
        x[512 + h] = ctx;
        x[h] = emb[a * 512 + h];
    }
}

// K5: gx = b_ih + x @ W_ih.T  (wave-cooperative)
__global__ __launch_bounds__(256) void k_gx2(const float* __restrict__ W_ih,
        const float* __restrict__ b_ih, float* __restrict__ ws) {
    int gw = blockIdx.x * 4 + (threadIdx.x >> 6);
    int rowbase = gw * 16;   // < 1536
    wave_gemv16<16>(W_ih + (size_t)rowbase * 1024, 1024,
                    ws + WS_X, 1024, b_ih + rowbase,
                    ws + WS_GX, 1536, rowbase);
}

// K6: GRU combine -> h1, write outputs + y = [h1 | context]
__global__ __launch_bounds__(256) void k_h1(const float* __restrict__ last_hidden,
        float* __restrict__ ws, float* __restrict__ out) {
    int i = blockIdx.x * 256 + threadIdx.x;   // < 8192
    int b = i >> 9, h = i & 511;
    const float* gx = ws + WS_GX + b * 1536;
    const float* gh = ws + WS_GH + b * 1536;
    float r = 1.f / (1.f + expf(-(gx[h] + gh[h])));
    float z = 1.f / (1.f + expf(-(gx[512 + h] + gh[512 + h])));
    float n = tanhf(gx[1024 + h] + r * gh[1024 + h]);
    float h0v = last_hidden[b * 512 + h];
    float h1 = (1.f - z) * n + z * h0v;
    out[i] = h1;
    out[8192 + i] = h1;
    ws[WS_Y + b * 1024 + h] = h1;
    ws[WS_Y + b * 1024 + 512 + h] = ws[WS_X + b * 1024 + 512 + h];
}

// K7: gen_logit = proj_b + y @ proj_W.T  (wave-cooperative, bias fused)
__global__ __launch_bounds__(256) void k_gen2(const float* __restrict__ proj_W,
        const float* __restrict__ proj_b, float* __restrict__ ws) {
    int gw = blockIdx.x * 4 + (threadIdx.x >> 6);
    int rowbase = gw * 16;   // < 32000
    wave_gemv16<16>(proj_W + (size_t)rowbase * 1024, 1024,
                    ws + WS_Y, 1024, proj_b + rowbase,
                    ws + WS_GL, V_SZ, rowbase);
}

// K9: copy scores -> exp weights w_t, m_b
__global__ __launch_bounds__(256) void k_copyscore(float* __restrict__ ws) {
    int b = blockIdx.x, tid = threadIdx.x;
    int t = tid >> 2, q = tid & 3;
    const float* tc = ws + WS_TANHC + (b * 64 + t) * 512;
    const float* h1 = ws + WS_Y + b * 1024;
    float s = 0.f;
    for (int i = 0; i < 128; i += 4) {
        int h = q * 128 + i;
        s += dot4(*(const float4*)(tc + h), *(const float4*)(h1 + h));
    }
    s += __shfl_xor(s, 1);
    s += __shfl_xor(s, 2);
    __shared__ float uc[64];
    if (q == 0) uc[t] = s;
    __syncthreads();
    if (tid < 64) {
        float v = uc[tid];
        float m = v;
        #pragma unroll
        for (int k = 32; k >= 1; k >>= 1) m = fmaxf(m, __shfl_xor(m, k));
        ws[WS_WT + b * 64 + tid] = expf(v - m);
        if (tid == 0) ws[WS_MB + b] = m;
    }
}

// K10: ucs_v[b][v] = log(sum_t w[t]*sparse[b][t][v]) + m_b  (float4)
__global__ __launch_bounds__(256) void k_ucsv(const float* __restrict__ sparse,
        float* __restrict__ ws) {
    int b = blockIdx.y;
    int v4 = (blockIdx.x * 256 + threadIdx.x) * 4;
    __shared__ float wsm[64];
    if (threadIdx.x < 64) wsm[threadIdx.x] = ws[WS_WT + b * 64 + threadIdx.x];
    __syncthreads();
    if (v4 >= VT_SZ) return;
    const float* sp = sparse + (size_t)b * 64 * VT_SZ + v4;
    float4 acc = make_float4(0.f, 0.f, 0.f, 0.f);
    #pragma unroll 4
    for (int t = 0; t < 64; ++t) {
        float w = wsm[t];
        float4 s = *(const float4*)(sp + (size_t)t * VT_SZ);
        acc.x = fmaf(w, s.x, acc.x);
        acc.y = fmaf(w, s.y, acc.y);
        acc.z = fmaf(w, s.z, acc.z);
        acc.w = fmaf(w, s.w, acc.w);
    }
    float m = ws[WS_MB + b];
    float4 r;
    r.x = logf(acc.x) + m; r.y = logf(acc.y) + m;
    r.z = logf(acc.z) + m; r.w = logf(acc.w) + m;
    *(float4*)(ws + WS_UCSV + (size_t)b * VT_SZ + v4) = r;
}

// K11a: per-chunk softmax stats (max, sumexp) over [gen_logit | ucs_v]
__global__ __launch_bounds__(256) void k_fstat(float* __restrict__ ws) {
    int b = blockIdx.x, c = blockIdx.y;   // 16 x 8, chunk = 8008 elems
    int tid = threadIdx.x;
    const float* gl = ws + WS_GL + (size_t)b * V_SZ;
    const float* uv = ws + WS_UCSV + (size_t)b * VT_SZ;
    int i0 = c * 8008, i1 = i0 + 8008;
    float m = -3.0e38f;
    for (int i = i0 + tid; i < i1; i += 256) {
        float v = (i < V_SZ) ? gl[i] : uv[i - V_SZ];
        m = fmaxf(m, v);
    }
    #pragma unroll
    for (int k = 32; k >= 1; k >>= 1) m = fmaxf(m, __shfl_xor(m, k));
    __shared__ float red[4];
    __shared__ float Msh;
    if ((tid & 63) == 0) red[tid >> 6] = m;
    __syncthreads();
    if (tid == 0) Msh = fmaxf(fmaxf(red[0], red[1]), fmaxf(red[2], red[3]));
    __syncthreads();
    float M = Msh;
    float s = 0.f;
    for (int i = i0 + tid; i < i1; i += 256) {
        float v = (i < V_SZ) ? gl[i] : uv[i - V_SZ];
        s += expf(v - M);
    }
    #pragma unroll
    for (int k = 32; k >= 1; k >>= 1) s += __shfl_xor(s, k);
    if ((tid & 63) == 0) red[tid >> 6] = s;
    __syncthreads();
    if (tid == 0) {
        ws[WS_FST + (b * 8 + c) * 2 + 0] = M;
        ws[WS_FST + (b * 8 + c) * 2 + 1] = red[0] + red[1] + red[2] + red[3];
    }
}

// K11b: merge stats, write proba
__global__ __launch_bounds__(256) void k_fwrite(float* __restrict__ ws,
        float* __restrict__ out) {
    int b = blockIdx.y;
    int i4 = (blockIdx.x * 256 + threadIdx.x) * 4;
    const float* st = ws + WS_FST + b * 16;
    float M = -3.0e38f;
    #pragma unroll
    for (int c = 0; c < 8; ++c) M = fmaxf(M, st[c * 2]);
    float S = 0.f;
    #pragma unroll
    for (int c = 0; c < 8; ++c) S += st[c * 2 + 1] * expf(st[c * 2] - M);
    float invS = 1.f / S;
    if (i4 >= VT_SZ) return;
    const float* gl = ws + WS_GL + (size_t)b * V_SZ;
    const float* uv = ws + WS_UCSV + (size_t)b * VT_SZ;
    float4 u4 = *(const float4*)(uv + i4);
    float4 r;
    r.x = expf(u4.x - M) * invS;
    r.y = expf(u4.y - M) * invS;
    r.z = expf(u4.z - M) * invS;
    r.w = expf(u4.w - M) * invS;
    if (i4 < V_SZ) {   // V_SZ % 4 == 0 so the whole quad is in the gen region
        float4 g4 = *(const float4*)(gl + i4);
        r.x += expf(g4.x - M) * invS;
        r.y += expf(g4.y - M) * invS;
        r.z += expf(g4.z - M) * invS;
        r.w += expf(g4.w - M) * invS;
    }
    *(float4*)(out + 16384 + (size_t)b * VT_SZ + i4) = r;
}

extern "C" void kernel_launch(void* const* d_in, const int* in_sizes, int n_in,
                              void* d_out, int out_size, void* d_ws, size_t ws_size,
                              hipStream_t stream) {
    (void)in_sizes; (void)n_in; (void)out_size; (void)ws_size;
    const float* u_enc   = (const float*)d_in[0];
    const int*   a_tm1   = (const int*)d_in[1];
    const float* last_h  = (const float*)d_in[2];
    // d_in[3] u_input_np unused
    const float* sparse  = (const float*)d_in[4];
    const float* emb     = (const float*)d_in[5];
    const float* W_ih    = (const float*)d_in[6];
    const float* b_ih    = (const float*)d_in[7];
    const float* W_hh    = (const float*)d_in[8];
    const float* b_hh    = (const float*)d_in[9];
    const float* proj_W  = (const float*)d_in[10];
    const float* proj_b  = (const float*)d_in[11];
    const float* attn_W  = (const float*)d_in[12];
    const float* attn_b  = (const float*)d_in[13];
    const float* attn_v  = (const float*)d_in[14];
    const float* copy_W  = (const float*)d_in[15];
    const float* copy_b  = (const float*)d_in[16];
    float* ws  = (float*)d_ws;
    float* out = (float*)d_out;

    hipLaunchKernelGGL(k_prep2, dim3(32), dim3(256), 0, stream,
                       last_h, attn_W, attn_b, W_hh, b_hh, ws);
    hipLaunchKernelGGL(k_encgemm, dim3(16, 16), dim3(256), 0, stream,
                       u_enc, attn_W, copy_W, copy_b, ws);
    hipLaunchKernelGGL(k_attn_e, dim3(16, 8), dim3(256), 0, stream, attn_v, ws);
    hipLaunchKernelGGL(k_attn_ctx, dim3(16), dim3(256), 0, stream, u_enc, a_tm1, emb, ws);
    hipLaunchKernelGGL(k_gx2, dim3(24), dim3(256), 0, stream, W_ih, b_ih, ws);
    hipLaunchKernelGGL(k_h1, dim3(32), dim3(256), 0, stream, last_h, ws, out);
    hipLaunchKernelGGL(k_gen2, dim3(500), dim3(256), 0, stream, proj_W, proj_b, ws);
    hipLaunchKernelGGL(k_copyscore, dim3(16), dim3(256), 0, stream, ws);
    hipLaunchKernelGGL(k_ucsv, dim3(32, 16), dim3(256), 0, stream, sparse, ws);
    hipLaunchKernelGGL(k_fstat, dim3(16, 8), dim3(256), 0, stream, ws);
    hipLaunchKernelGGL(k_fwrite, dim3(32, 16), dim3(256), 0, stream, ws, out);
}